// Round 11
// baseline (115.456 us; speedup 1.0000x reference)
//
#include <hip/hip_runtime.h>

#define CC 30                      // 5*NB + NC
#define TPW 64                     // cells per wave-tile
#define HALF 32                    // cells per half-tile (pipeline granularity)
#define WPB 4                      // waves per block (256-thread blocks)
#define HALF_FLOATS (HALF * CC)    // 960 floats = 3840 B per array per half
#define HALF_VEC4   (HALF_FLOATS / 4)   // 240 float4 per array per half

#define AS1 __attribute__((address_space(1)))
#define AS3 __attribute__((address_space(3)))

// async 16B/lane DMA: lane i of the wave writes lds_base + i*16 (wave-uniform dst)
__device__ __forceinline__ void dma16(const float4* gsrc_lane, float4* lds_base) {
    __builtin_amdgcn_global_load_lds((const AS1 unsigned int*)gsrc_lane,
                                     (AS3 unsigned int*)lds_base, 16, 0, 0);
}

// Issue DMA for one 32-cell half: 240 float4 per array = 3 full chunks + 48-lane tail,
// for both arrays -> exactly 8 vmem instructions.
__device__ __forceinline__ void prefetch_half(const float* __restrict__ in,
                                              const float* __restrict__ tg,
                                              size_t cell_base,   // multiple of 32 -> 16B-aligned
                                              float* lin, float* ltg, int lane) {
    const float4* gin = (const float4*)(in + cell_base * CC);
    const float4* gtg = (const float4*)(tg + cell_base * CC);
    float4* vin = (float4*)lin;
    float4* vtg = (float4*)ltg;
    #pragma unroll
    for (int k = 0; k < 3; ++k) {
        dma16(gin + k * 64 + lane, vin + k * 64);
        dma16(gtg + k * 64 + lane, vtg + k * 64);
    }
    if (lane < 48) {                       // float4 idx 192..239
        dma16(gin + 192 + lane, vin + 192);
        dma16(gtg + 192 + lane, vtg + 192);
    }
}

// ---- 32 cells with 64 lanes: lane 2c+h owns cell c's predicted box h ----
__device__ __forceinline__ void compute_half(const float* __restrict__ lin,
                                             const float* __restrict__ ltg,
                                             int lane, float inv_gs,
                                             float& a_boxes, float& a_conf, float& a_class) {
    const int c = lane >> 1;
    const int h = lane & 1;
    const float* f = lin + c * CC;
    const float* t = ltg + c * CC;

    // own predicted box (h=0: f[0..4], h=1: f[5..9])
    const int hb = 5 * h;
    const float px  = f[hb + 0];
    const float py  = f[hb + 1];
    const float pw  = f[hb + 2];
    const float phh = f[hb + 3];
    const float pc  = f[hb + 4];

    // target box + confidences (pair-broadcast reads)
    const float bt0 = t[0], bt1 = t[1], bt2 = t[2], bt3 = t[3];
    const float conf_t  = t[4];
    const float tconf_h = f == t ? 0.0f : t[hb + 4];   // t[4] or t[9]
    const float coord = (conf_t > 0.0f)  ? 1.0f : 0.0f;
    const float noobj = (conf_t == 0.0f) ? 1.0f : 0.0f;

    // noobj contribution split across the pair: lane h does (f[5h+4]-t[5h+4])^2
    const float dn = pc - tconf_h;

    // target corners
    const float ttx = bt0 * inv_gs, tty = bt1 * inv_gs;
    const float txmin = ttx - 0.5f * bt2, tymin = tty - 0.5f * bt3;
    const float txmax = ttx + 0.5f * bt2, tymax = tty + 0.5f * bt3;
    const float tarea = (txmax - txmin) * (tymax - tymin);

    // own IOU
    const float cx = px * inv_gs, cy = py * inv_gs;
    const float xmin = cx - 0.5f * pw, ymin = cy - 0.5f * phh;
    const float xmax = cx + 0.5f * pw, ymax = cy + 0.5f * phh;
    const float wx = fmaxf(fminf(xmax, txmax) - fmaxf(xmin, txmin), 0.0f);
    const float wy = fmaxf(fminf(ymax, tymax) - fmaxf(ymin, tymin), 0.0f);
    const float inter = wx * wy;
    const float parea = (xmax - xmin) * (ymax - ymin);
    const float iou_mine = inter / (parea + tarea - inter);

    // pair exchange
    const float iou_other = __shfl_xor(iou_mine, 1, 64);
    const float iou0 = h ? iou_other : iou_mine;
    const float iou1 = h ? iou_mine  : iou_other;
    const bool  sel1 = iou1 > iou0;            // jnp.argmax: first max on ties
    const float max_iou = fmaxf(iou0, iou1);
    const float own = ((h == 1) == sel1) ? 1.0f : 0.0f;

    const float dx = px - bt0, dy = py - bt1;
    const float sw = sqrtf(pw)  - sqrtf(bt2);
    const float sh = sqrtf(phh) - sqrtf(bt3);
    const float dob = pc - max_iou;

    a_boxes += own * coord * (dx * dx + dy * dy + sw * sw + sh * sh);
    a_conf  += own * coord * (dob * dob) + 0.5f * noobj * dn * dn;

    // class loss split: lane h handles float2 idx 5+5h .. 9+5h (10 channels)
    const float2* f2 = (const float2*)f;
    const float2* t2 = (const float2*)t;
    float l = 0.0f;
    #pragma unroll
    for (int j = 0; j < 5; ++j) {
        const float2 fv = f2[5 + 5 * h + j];
        const float2 tv = t2[5 + 5 * h + j];
        const float gx = fv.x - tv.x;
        const float gy = fv.y - tv.y;
        l += gx * gx + gy * gy;
    }
    a_class += coord * l;
}

// ---- scalar path (global pointers) for the <64-cell remainder, used in finalize ----
__device__ __forceinline__ void cell_losses_global(const float* __restrict__ f,
                                                   const float* __restrict__ t,
                                                   float& o_boxes, float& o_conf, float& o_cls) {
    const float inv_gs = 0.14285714285714285f;
    const float conf_t = t[4];
    const float coord  = (conf_t > 0.0f)  ? 1.0f : 0.0f;
    const float noobj  = (conf_t == 0.0f) ? 1.0f : 0.0f;
    const float d0 = f[4] - t[4];
    const float d1 = f[9] - t[9];
    const float l_noobj = noobj * (d0 * d0 + d1 * d1);
    const float bt0 = t[0], bt1 = t[1], bt2 = t[2], bt3 = t[3];
    const float ttx = bt0 * inv_gs, tty = bt1 * inv_gs;
    const float txmin = ttx - 0.5f * bt2, tymin = tty - 0.5f * bt3;
    const float txmax = ttx + 0.5f * bt2, tymax = tty + 0.5f * bt3;
    const float tarea = (txmax - txmin) * (tymax - tymin);
    float iou0, iou1;
    {
        const float cx = f[0] * inv_gs, cy = f[1] * inv_gs;
        const float xmin = cx - 0.5f * f[2], ymin = cy - 0.5f * f[3];
        const float xmax = cx + 0.5f * f[2], ymax = cy + 0.5f * f[3];
        const float wx = fmaxf(fminf(xmax, txmax) - fmaxf(xmin, txmin), 0.0f);
        const float wy = fmaxf(fminf(ymax, tymax) - fmaxf(ymin, tymin), 0.0f);
        const float inter = wx * wy;
        const float parea = (xmax - xmin) * (ymax - ymin);
        iou0 = inter / (parea + tarea - inter);
    }
    {
        const float cx = f[5] * inv_gs, cy = f[6] * inv_gs;
        const float xmin = cx - 0.5f * f[7], ymin = cy - 0.5f * f[8];
        const float xmax = cx + 0.5f * f[7], ymax = cy + 0.5f * f[8];
        const float wx = fmaxf(fminf(xmax, txmax) - fmaxf(xmin, txmin), 0.0f);
        const float wy = fmaxf(fminf(ymax, tymax) - fmaxf(ymin, tymin), 0.0f);
        const float inter = wx * wy;
        const float parea = (xmax - xmin) * (ymax - ymin);
        iou1 = inter / (parea + tarea - inter);
    }
    const bool  sel1    = iou1 > iou0;
    const float max_iou = fmaxf(iou0, iou1);
    const float rp0 = sel1 ? f[5] : f[0];
    const float rp1 = sel1 ? f[6] : f[1];
    const float rp2 = sel1 ? f[7] : f[2];
    const float rp3 = sel1 ? f[8] : f[3];
    const float rp4 = sel1 ? f[9] : f[4];
    const float dx = rp0 - bt0, dy = rp1 - bt1;
    const float sw = sqrtf(rp2) - sqrtf(bt2);
    const float sh = sqrtf(rp3) - sqrtf(bt3);
    const float dob = rp4 - max_iou;
    float l_cls = 0.0f;
    #pragma unroll
    for (int j = 10; j < 30; ++j) {
        const float d = f[j] - t[j];
        l_cls += d * d;
    }
    o_boxes += coord * (dx * dx + dy * dy + sw * sw + sh * sh);
    o_conf  += coord * (dob * dob) + 0.5f * l_noobj;
    o_cls   += coord * l_cls;
}

// -------- main: wave-private half-tile ping-pong, fine-grained vmcnt(8), 8 waves/CU --------
__global__ __launch_bounds__(256) void yolo_main(
        const float* __restrict__ in,
        const float* __restrict__ tg,
        float* __restrict__ ws,
        int ncells, int nwaves_total, int pstride) {
    // per wave: 2 half-buffers x (in 960 + tg 960) = 3840 floats = 15360 B; x4 waves
    __shared__ float s_lds[WPB * 2 * 2 * HALF_FLOATS];

    const int tid   = threadIdx.x;
    const int lane  = tid & 63;
    const int wave  = tid >> 6;
    const int gwave = blockIdx.x * WPB + wave;

    float* base = s_lds + wave * (2 * 2 * HALF_FLOATS);
    float* bin[2] = { base,                    base + 2 * HALF_FLOATS };
    float* btg[2] = { base + HALF_FLOATS,      base + 3 * HALF_FLOATS };

    const int nfull = ncells / TPW;             // full 64-cell tiles (remainder -> finalize)
    const float inv_gs = 0.14285714285714285f;  // 1/7 (abs err ~1e-7 vs 0.4 threshold)

    float a_boxes = 0.0f, a_conf = 0.0f, a_class = 0.0f;

    int ct = gwave;                             // tile of current half
    if (ct < nfull) {
        prefetch_half(in, tg, (size_t)ct * TPW, bin[0], btg[0], lane);   // (ct, half 0)
        int chalf = 0;
        int cur = 0;
        while (true) {
            // next half in this wave's sequence: (t,0)->(t,1)->(t+stride,0)->...
            int nt = ct, nh = chalf + 1;
            if (nh == 2) { nh = 0; nt = ct + nwaves_total; }
            const bool has_next = (nt < nfull);

            // old ds_reads of the target buffer retired before DMA overwrites it
            asm volatile("s_waitcnt lgkmcnt(0)" ::: "memory");
            __builtin_amdgcn_wave_barrier();
            if (has_next)
                prefetch_half(in, tg, (size_t)nt * TPW + (size_t)nh * HALF,
                              bin[cur ^ 1], btg[cur ^ 1], lane);
            __builtin_amdgcn_wave_barrier();
            // wait ONLY for current half's 8 DMAs (8 newer stay in flight)
            if (has_next) asm volatile("s_waitcnt vmcnt(8)" ::: "memory");
            else          asm volatile("s_waitcnt vmcnt(0)" ::: "memory");
            __builtin_amdgcn_wave_barrier();
            compute_half(bin[cur], btg[cur], lane, inv_gs, a_boxes, a_conf, a_class);
            __builtin_amdgcn_wave_barrier();

            if (!has_next) break;
            ct = nt; chalf = nh; cur ^= 1;
        }
    }

    // ---- wave-64 shuffle reduce; one partial triple per WAVE ----
    #pragma unroll
    for (int off = 32; off > 0; off >>= 1) {
        a_boxes += __shfl_down(a_boxes, off, 64);
        a_conf  += __shfl_down(a_conf,  off, 64);
        a_class += __shfl_down(a_class, off, 64);
    }
    if (lane == 0) {
        ws[gwave]               = a_boxes;
        ws[gwave + pstride]     = a_conf;
        ws[gwave + 2 * pstride] = a_class;
    }
}

// ---------------- finalize: sum per-wave partials + remainder cells, scale, write out ----------------
__global__ __launch_bounds__(256) void yolo_finalize(
        const float* __restrict__ in,
        const float* __restrict__ tg,
        const float* __restrict__ ws, float* __restrict__ out,
        int nparts, int pstride, int rem_base, int rem, float inv_bs) {
    float b = 0.0f, c = 0.0f, k = 0.0f;
    for (int i = threadIdx.x; i < nparts; i += 256) {
        b += ws[i];
        c += ws[i + pstride];
        k += ws[i + 2 * pstride];
    }
    if ((int)threadIdx.x < rem) {
        const size_t cell = (size_t)(rem_base + threadIdx.x) * CC;
        cell_losses_global(in + cell, tg + cell, b, c, k);
    }
    #pragma unroll
    for (int off = 32; off > 0; off >>= 1) {
        b += __shfl_down(b, off, 64);
        c += __shfl_down(c, off, 64);
        k += __shfl_down(k, off, 64);
    }
    __shared__ float s_red[4][3];
    const int wave = threadIdx.x >> 6;
    if ((threadIdx.x & 63) == 0) {
        s_red[wave][0] = b;
        s_red[wave][1] = c;
        s_red[wave][2] = k;
    }
    __syncthreads();
    if (threadIdx.x == 0) {
        const float tb = s_red[0][0] + s_red[1][0] + s_red[2][0] + s_red[3][0];
        const float tc = s_red[0][1] + s_red[1][1] + s_red[2][1] + s_red[3][1];
        const float tk = s_red[0][2] + s_red[1][2] + s_red[2][2] + s_red[3][2];
        out[0] = 0.5f * tb * inv_bs;   // LAMBDA_COORD*(xy+wh)/bs
        out[1] = tc * inv_bs;          // (obj + 0.5*noobj)/bs
        out[2] = tk * inv_bs;          // class/bs
    }
}

extern "C" void kernel_launch(void* const* d_in, const int* in_sizes, int n_in,
                              void* d_out, int out_size, void* d_ws, size_t ws_size,
                              hipStream_t stream) {
    const float* in = (const float*)d_in[0];
    const float* tg = (const float*)d_in[1];
    float* out = (float*)d_out;
    float* ws  = (float*)d_ws;

    const int ncells = in_sizes[0] / CC;          // B * 49
    const int B = ncells / 49;
    const float inv_bs = 1.0f / (float)B;

    // 61.4 KB LDS/block (256 thr) -> 2 blocks/CU = 8 waves/CU, 512 blocks co-resident.
    const int nblocks = 512;
    const int nwaves  = nblocks * WPB;            // 2048
    const int pstride = nwaves;
    const int nfull   = ncells / TPW;
    const int rem     = ncells - nfull * TPW;     // 0 at B=8192

    yolo_main<<<nblocks, 256, 0, stream>>>(in, tg, ws, ncells, nwaves, pstride);
    yolo_finalize<<<1, 256, 0, stream>>>(in, tg, ws, out, nwaves, pstride,
                                         nfull * TPW, rem, inv_bs);
}